// Round 3
// baseline (178.685 us; speedup 1.0000x reference)
//
#include <hip/hip_runtime.h>

#define NN 100000
#define NE 1600000
#define HID 64
#define NBUK 391              // buckets of 256 node ids: (NN+255)/256
#define SRCBITS 17
#define SRCMASK 0x1FFFF
#define EBLK 4096             // edges per block
#define GE2 ((NE + EBLK - 1) / EBLK)        // 391 edge-blocks
#define BSTRIDE 6144          // fixed bbuf slots per bucket (mean 4096, 32 sigma headroom)

typedef __attribute__((ext_vector_type(8))) short bf16x8;
typedef __attribute__((ext_vector_type(4))) float f32x4;

__device__ __forceinline__ float bf2f(unsigned short u) {
    return __uint_as_float(((unsigned int)u) << 16);
}
__device__ __forceinline__ unsigned short f2bf(float f) {   // RTNE
    unsigned int x = __float_as_uint(f);
    return (unsigned short)((x + 0x7FFFu + ((x >> 16) & 1u)) >> 16);
}
__device__ __forceinline__ float bflo(unsigned int u) { return __uint_as_float(u << 16); }
__device__ __forceinline__ float bfhi(unsigned int u) { return __uint_as_float(u & 0xFFFF0000u); }

// ---- fused hist + place: stage 4096 edges in LDS, histogram, reserve ------
// per-bucket space via global atomics (fixed-stride regions => NO global
// scan), scatter packed edges. Last-arriving block (arrival counter, no
// spin) exclusive-scans bucket totals -> global csr bases.
__global__ void __launch_bounds__(256)
k_fill1(const int* __restrict__ ei, int* __restrict__ gcnt,
        int* __restrict__ arrival, int* __restrict__ bucketBase,
        unsigned int* __restrict__ bbuf) {
    __shared__ int s_src[EBLK];   // 16 KB
    __shared__ int s_dst[EBLK];   // 16 KB
    __shared__ int s_hist[NBUK];  // hist, then cur (absolute positions)
    __shared__ int s_tmp[256];
    __shared__ int s_flag;
    __shared__ int s_last;
    int t = threadIdx.x;  // 256
    int b = blockIdx.x;

    for (int i = t; i < NBUK; i += 256) s_hist[i] = 0;
    if (t < 64) {   // int64 edges have all-zero odd int32 words
        unsigned long long bal = __ballot(ei[2 * t + 1] != 0);
        if (t == 0) s_flag = (bal == 0ULL) ? 1 : 0;  // 1 => int64 layout
    }
    __syncthreads();
    int f = s_flag;
    int base = b * EBLK;
    int m = NE - base; if (m > EBLK) m = EBLK;

    if (f) {                               // int64: int4 = 2 edges' words
        const int4* ps = (const int4*)ei;
        const int4* pd = (const int4*)(ei + 2 * (size_t)NE);
#pragma unroll
        for (int k = 0; k < EBLK / 512; ++k) {
            int e = base + k * 512 + t * 2;
            if (e < NE) {                  // NE even, e even -> e+1 valid
                int4 vs = ps[e >> 1];
                int4 vd = pd[e >> 1];
                int l = e - base;
                s_src[l] = vs.x;     s_dst[l] = vd.x;
                s_src[l + 1] = vs.z; s_dst[l + 1] = vd.z;
                atomicAdd(&s_hist[vd.x >> 8], 1);
                atomicAdd(&s_hist[vd.z >> 8], 1);
            }
        }
    } else {                               // int32: int4 = 4 edges
        const int4* ps = (const int4*)ei;
        const int4* pd = (const int4*)(ei + NE);
#pragma unroll
        for (int k = 0; k < EBLK / 1024; ++k) {
            int e = base + k * 1024 + t * 4;
            if (e < NE) {                  // NE % 4 == 0 -> whole quad valid
                int4 vs = ps[e >> 2];
                int4 vd = pd[e >> 2];
                int l = e - base;
                s_src[l] = vs.x; s_src[l + 1] = vs.y; s_src[l + 2] = vs.z; s_src[l + 3] = vs.w;
                s_dst[l] = vd.x; s_dst[l + 1] = vd.y; s_dst[l + 2] = vd.z; s_dst[l + 3] = vd.w;
                atomicAdd(&s_hist[vd.x >> 8], 1);
                atomicAdd(&s_hist[vd.y >> 8], 1);
                atomicAdd(&s_hist[vd.z >> 8], 1);
                atomicAdd(&s_hist[vd.w >> 8], 1);
            }
        }
    }
    __syncthreads();
    // reserve per-bucket chunks; cur[i] = absolute bbuf position
    for (int i = t; i < NBUK; i += 256) {
        int c = s_hist[i];
        int r = atomicAdd(&gcnt[i], c);            // device-scope, L2-serialized
        s_hist[i] = i * BSTRIDE + r;
    }
    __syncthreads();
    // scatter staged edges
    for (int e = t; e < m; e += 256) {
        int d = s_dst[e];
        int p = atomicAdd(&s_hist[d >> 8], 1);
        bbuf[p] = ((unsigned int)(d & 255) << SRCBITS) | (unsigned int)s_src[e];
    }
    __syncthreads();
    if (t == 0) s_last = atomicAdd(arrival, 1);    // after ALL this block's work
    __syncthreads();
    if (s_last == GE2 - 1) {
        // last block: exclusive scan of gcnt[0..NBUK-1] -> bucketBase[0..NBUK]
        int i0 = 2 * t, i1 = 2 * t + 1;
        int v0 = (i0 < NBUK) ? atomicAdd(&gcnt[i0], 0) : 0;   // coherent read
        int v1 = (i1 < NBUK) ? atomicAdd(&gcnt[i1], 0) : 0;
        int ps2 = v0 + v1;
        s_tmp[t] = ps2; __syncthreads();
        for (int off = 1; off < 256; off <<= 1) {
            int u = (t >= off) ? s_tmp[t - off] : 0;
            __syncthreads();
            s_tmp[t] += u;
            __syncthreads();
        }
        int run = s_tmp[t] - ps2;
        if (i0 <= NBUK) bucketBase[i0] = run;
        if (i1 <= NBUK) bucketBase[i1] = run + v0;
    }
}

// ---- pass B: per-bucket 256-slot sort -> cnt/offs/dinv/xs + csr ------------
__global__ void k_passB(const unsigned int* __restrict__ bbuf, const int* __restrict__ gcnt,
                        const int* __restrict__ bucketBase, const float* __restrict__ x,
                        int* __restrict__ cnt, int* __restrict__ offs,
                        float* __restrict__ dinv, float* __restrict__ xs,
                        int* __restrict__ csr) {
    __shared__ int hist[256];
    __shared__ int scn[256];
    __shared__ int cur[256];
    int t = threadIdx.x;  // 256
    int b = blockIdx.x;
    int sz = gcnt[b];
    int csrbase = bucketBase[b];
    const unsigned int* buf = bbuf + (size_t)b * BSTRIDE;
    hist[t] = 0;
    __syncthreads();
    for (int e = t; e < sz; e += 256)
        atomicAdd(&hist[buf[e] >> SRCBITS], 1);
    __syncthreads();
    int deg = hist[t];
    scn[t] = deg; __syncthreads();
    for (int off = 1; off < 256; off <<= 1) {
        int u = (t >= off) ? scn[t - off] : 0;
        __syncthreads();
        scn[t] += u;
        __syncthreads();
    }
    int myoff = csrbase + scn[t] - deg;
    int node = b * 256 + t;
    if (node < NN) {
        cnt[node]  = deg;
        offs[node] = myoff;
        float d = 1.0f / sqrtf((float)(deg + 1));
        dinv[node] = d;
        float4 xv = ((const float4*)x)[node];
        float4 o; o.x = d * xv.x; o.y = d * xv.y; o.z = d * xv.z; o.w = d * xv.w;
        ((float4*)xs)[node] = o;
    }
    cur[t] = myoff;
    __syncthreads();
    for (int e = t; e < sz; e += 256) {
        unsigned int u = buf[e];
        int p = atomicAdd(&cur[u >> SRCBITS], 1);
        csr[p] = (int)(u & SRCMASK);
    }
}

// ---- fused: layer-1 aggregate (4 thr/node) + h1 + MFMA h1@W2 -> hs ---------
// 64 nodes/block, 256 threads. agg = dinv*(sum_nbr xs[s] + xs[self]).
// mfma_f32_16x16x32_bf16: A[m=lane&15][k=quad*8+j]; D col=lane&15, row=quad*4+reg.
__global__ void k_mm2(const float* __restrict__ xs, const int* __restrict__ cnt,
                      const int* __restrict__ offs, const int* __restrict__ csr,
                      const float* __restrict__ dinv,
                      const float* __restrict__ W1, const float* __restrict__ b1,
                      const float* __restrict__ W2, unsigned short* __restrict__ hs) {
    __shared__ unsigned short h1b[64 * 72];   // [localNode][k], bf16, pad 72
    __shared__ unsigned short w2t[64 * 72];   // [n][k], bf16 (W2 transposed)
    __shared__ float4 sPart[256];             // per-(part,node) partial sums
    __shared__ float4 sAgg[64];
    __shared__ float4 sXs[64];
    __shared__ float sW1[256];
    __shared__ float sb1[64];
    __shared__ float sdv[64];
    __shared__ int scnt[64];
    __shared__ int soff[64];
    int t = threadIdx.x;  // 256
    int base = blockIdx.x * 64;
    if (t < 64) {
        int g = base + t;
        bool ok = (g < NN);
        scnt[t] = ok ? cnt[g] : 0;
        soff[t] = ok ? offs[g] : 0;
        sdv[t]  = ok ? dinv[g] : 0.f;
        sXs[t]  = ok ? ((const float4*)xs)[g] : make_float4(0.f, 0.f, 0.f, 0.f);
        sb1[t]  = b1[t];
    }
    sW1[t] = W1[t];
    for (int i = t; i < 4096; i += 256) {     // W2 [k][n] fp32 -> w2t [n][k] bf16
        int k = i >> 6, n = i & 63;
        w2t[n * 72 + k] = f2bf(W2[i]);
    }
    if (blockIdx.x == 0 && t >= 128 && t < 192) hs[NN * 64 + (t - 128)] = 0;  // sentinel row
    __syncthreads();
    // aggregation: node_l = t&63, part = t>>6 handles j = part, part+4, ...
    {
        int node_l = t & 63, part = t >> 6;
        int n = scnt[node_l], b0 = soff[node_l];
        float4 s = make_float4(0.f, 0.f, 0.f, 0.f);
        int j = part;
        for (; j + 4 < n; j += 8) {           // 2 independent loads in flight
            int s0 = csr[b0 + j], s1 = csr[b0 + j + 4];
            float4 v0 = ((const float4*)xs)[s0];
            float4 v1 = ((const float4*)xs)[s1];
            s.x += v0.x + v1.x; s.y += v0.y + v1.y;
            s.z += v0.z + v1.z; s.w += v0.w + v1.w;
        }
        for (; j < n; j += 4) {
            int s0 = csr[b0 + j];
            float4 v = ((const float4*)xs)[s0];
            s.x += v.x; s.y += v.y; s.z += v.z; s.w += v.w;
        }
        sPart[t] = s;
    }
    __syncthreads();
    if (t < 64) {
        float4 a = sPart[t], b = sPart[t + 64], c = sPart[t + 128], d = sPart[t + 192];
        float4 xi = sXs[t];
        float dn = sdv[t];
        float4 o;
        o.x = dn * (a.x + b.x + c.x + d.x + xi.x);
        o.y = dn * (a.y + b.y + c.y + d.y + xi.y);
        o.z = dn * (a.z + b.z + c.z + d.z + xi.z);
        o.w = dn * (a.w + b.w + c.w + d.w + xi.w);
        sAgg[t] = o;
    }
    __syncthreads();
#pragma unroll
    for (int i = 0; i < 16; ++i) {            // h1 = relu(agg@W1+b1), bf16 to LDS
        int e = i * 256 + t;
        int nl = e >> 6, c = e & 63;
        float4 a = sAgg[nl];
        float h = fmaf(a.x, sW1[c], fmaf(a.y, sW1[64 + c],
                  fmaf(a.z, sW1[128 + c], fmaf(a.w, sW1[192 + c], sb1[c]))));
        h1b[nl * 72 + c] = f2bf(fmaxf(h, 0.f));
    }
    __syncthreads();
    int w = t >> 6, lane = t & 63, l15 = lane & 15, quad = lane >> 4;
    bf16x8 a0 = *(const bf16x8*)&h1b[(w * 16 + l15) * 72 + quad * 8];
    bf16x8 a1 = *(const bf16x8*)&h1b[(w * 16 + l15) * 72 + 32 + quad * 8];
    f32x4 acc[4];
#pragma unroll
    for (int nt = 0; nt < 4; ++nt) {
        bf16x8 bb0 = *(const bf16x8*)&w2t[(nt * 16 + l15) * 72 + quad * 8];
        bf16x8 bb1 = *(const bf16x8*)&w2t[(nt * 16 + l15) * 72 + 32 + quad * 8];
        f32x4 c = {0.f, 0.f, 0.f, 0.f};
        c = __builtin_amdgcn_mfma_f32_16x16x32_bf16(a0, bb0, c, 0, 0, 0);
        c = __builtin_amdgcn_mfma_f32_16x16x32_bf16(a1, bb1, c, 0, 0, 0);
        acc[nt] = c;
    }
#pragma unroll
    for (int nt = 0; nt < 4; ++nt) {
#pragma unroll
        for (int r = 0; r < 4; ++r) {
            int localn = w * 16 + quad * 4 + r;
            int g = base + localn;
            if (g < NN) hs[g * 64 + nt * 16 + l15] = f2bf(acc[nt][r] * sdv[localn]);
        }
    }
}

// ---- layer-2 gather + head: sentinel-padded flat schedule ------------------
// 4 nodes/block (1 wave each). Lane c: rg=c>>3 owns edges rg+8k (k=0..7),
// sl=c&7 owns 16B chunk (cols 8sl..8sl+7). myidx is sentinel NN for c>=n,
// so shfl needs no guards; all 8 row loads are independent (8 VMEM in
// flight/wave) and per-wave work is uniform regardless of degree.
__global__ void k_gather_head(const unsigned short* __restrict__ hs, const int* __restrict__ offs,
                              const int* __restrict__ cnt, const int* __restrict__ csr,
                              const float* __restrict__ dinv, const float* __restrict__ b2,
                              const float* __restrict__ Wl, const float* __restrict__ bl,
                              float* __restrict__ out) {
    int t = threadIdx.x;
    int node = blockIdx.x * 4 + (t >> 6);
    int c = t & 63;
    int rg = c >> 3;
    int sl = c & 7;
    int b = offs[node], n = cnt[node];
    const uint4* h4 = (const uint4*)hs;          // 8 uint4 per 64-col row
    int myidx = (c < n) ? csr[b + c] : NN;       // NN = zero sentinel row

    int s0 = __shfl(myidx, rg,      64);
    int s1 = __shfl(myidx, rg + 8,  64);
    int s2 = __shfl(myidx, rg + 16, 64);
    int s3 = __shfl(myidx, rg + 24, 64);
    int s4 = __shfl(myidx, rg + 32, 64);
    int s5 = __shfl(myidx, rg + 40, 64);
    int s6 = __shfl(myidx, rg + 48, 64);
    int s7 = __shfl(myidx, rg + 56, 64);
    uint4 u0 = h4[s0 * 8 + sl];
    uint4 u1 = h4[s1 * 8 + sl];
    uint4 u2 = h4[s2 * 8 + sl];
    uint4 u3 = h4[s3 * 8 + sl];
    uint4 u4 = h4[s4 * 8 + sl];
    uint4 u5 = h4[s5 * 8 + sl];
    uint4 u6 = h4[s6 * 8 + sl];
    uint4 u7 = h4[s7 * 8 + sl];

    float4 A = make_float4(0.f, 0.f, 0.f, 0.f);  // cols 8sl+0..3
    float4 B = make_float4(0.f, 0.f, 0.f, 0.f);  // cols 8sl+4..7
#define ACC(u) do { \
    A.x += bflo(u.x); A.y += bfhi(u.x); A.z += bflo(u.y); A.w += bfhi(u.y); \
    B.x += bflo(u.z); B.y += bfhi(u.z); B.z += bflo(u.w); B.w += bfhi(u.w); } while (0)
    ACC(u0); ACC(u1); ACC(u2); ACC(u3); ACC(u4); ACC(u5); ACC(u6); ACC(u7);

    for (int j = 64; j < n; j += 8) {            // rare: deg > 64
        int e = j + rg;
        int s = (e < n) ? csr[b + e] : NN;
        uint4 u = h4[s * 8 + sl];
        ACC(u);
    }
#undef ACC
    // reduce across rg (lane bits 3..5)
#pragma unroll
    for (int mask = 8; mask <= 32; mask <<= 1) {
        A.x += __shfl_xor(A.x, mask, 64); A.y += __shfl_xor(A.y, mask, 64);
        A.z += __shfl_xor(A.z, mask, 64); A.w += __shfl_xor(A.w, mask, 64);
        B.x += __shfl_xor(B.x, mask, 64); B.y += __shfl_xor(B.y, mask, 64);
        B.z += __shfl_xor(B.z, mask, 64); B.w += __shfl_xor(B.w, mask, 64);
    }
    uint4 uS = h4[node * 8 + sl];                // self loop, once
    A.x += bflo(uS.x); A.y += bfhi(uS.x); A.z += bflo(uS.y); A.w += bfhi(uS.y);
    B.x += bflo(uS.z); B.y += bfhi(uS.z); B.z += bflo(uS.w); B.w += bfhi(uS.w);

    float4 bvA = ((const float4*)b2)[sl * 2];
    float4 bvB = ((const float4*)b2)[sl * 2 + 1];
    float4 wvA = ((const float4*)Wl)[sl * 2];
    float4 wvB = ((const float4*)Wl)[sl * 2 + 1];
    float dn = dinv[node];
    float v = fmaxf(fmaf(dn, A.x, bvA.x), 0.f) * wvA.x
            + fmaxf(fmaf(dn, A.y, bvA.y), 0.f) * wvA.y
            + fmaxf(fmaf(dn, A.z, bvA.z), 0.f) * wvA.z
            + fmaxf(fmaf(dn, A.w, bvA.w), 0.f) * wvA.w
            + fmaxf(fmaf(dn, B.x, bvB.x), 0.f) * wvB.x
            + fmaxf(fmaf(dn, B.y, bvB.y), 0.f) * wvB.y
            + fmaxf(fmaf(dn, B.z, bvB.z), 0.f) * wvB.z
            + fmaxf(fmaf(dn, B.w, bvB.w), 0.f) * wvB.w;
    // reduce across sl (lane bits 0..2)
    v += __shfl_xor(v, 1, 64);
    v += __shfl_xor(v, 2, 64);
    v += __shfl_xor(v, 4, 64);
    if (c == 0) out[node] = v + bl[0];
}

extern "C" void kernel_launch(void* const* d_in, const int* in_sizes, int n_in,
                              void* d_out, int out_size, void* d_ws, size_t ws_size,
                              hipStream_t stream) {
    const float* x  = (const float*)d_in[0];
    const int*   ei = (const int*)d_in[1];
    const float* W1 = (const float*)d_in[2];
    const float* b1 = (const float*)d_in[3];
    const float* W2 = (const float*)d_in[4];
    const float* b2 = (const float*)d_in[5];
    const float* Wl = (const float*)d_in[6];
    const float* bl = (const float*)d_in[7];
    float* out = (float*)d_out;

    char* w = (char*)d_ws;
    float* dinv  = (float*)w;                  w += NN * 4;
    int*   cnt   = (int*)w;                    w += NN * 4;
    int*   offs  = (int*)w;                    w += NN * 4;
    int*   csr   = (int*)w;                    w += NE * 4;
    float* xs    = (float*)w;                  w += NN * 4 * 4;
    unsigned short* hs = (unsigned short*)w;   w += (size_t)(NN + 1) * HID * 2;     // 12.8 MB (+sentinel)
    int*   gcnt  = (int*)w;                    w += NBUK * 4;
    int*   arrival = (int*)w;                  w += 4;
    int*   bucketBase = (int*)w;               w += (NBUK + 1) * 4;
    w = (char*)(((size_t)w + 255) & ~(size_t)255);
    unsigned int* bbuf = (unsigned int*)w;     w += (size_t)NBUK * BSTRIDE * 4;     // 9.6 MB

    const int GMM = (NN + 63) / 64;        // 1563

    // zero gcnt + arrival (contiguous) each replay
    hipMemsetAsync(gcnt, 0, (NBUK + 1) * sizeof(int), stream);
    hipLaunchKernelGGL(k_fill1, dim3(GE2),  dim3(256), 0, stream,
                       ei, gcnt, arrival, bucketBase, bbuf);
    hipLaunchKernelGGL(k_passB, dim3(NBUK), dim3(256), 0, stream,
                       bbuf, gcnt, bucketBase, x, cnt, offs, dinv, xs, csr);
    hipLaunchKernelGGL(k_mm2, dim3(GMM), dim3(256), 0, stream,
                       xs, cnt, offs, csr, dinv, W1, b1, W2, hs);
    hipLaunchKernelGGL(k_gather_head, dim3(NN / 4), dim3(256), 0, stream,
                       hs, offs, cnt, csr, dinv, b2, Wl, bl, out);
}